// Round 5
// baseline (46.156 us; speedup 1.0000x reference)
//
#include <hip/hip_runtime.h>

// Cone-beam projection: D=W=H=128 volume, 180x180 detector, BATCH=4.
// out[b][0][i][j] = dx(b,i,j) * sum_{k=0..127} trilinear(vol, ray(b,i,j,k))
//
// Index-space ray, linear in k:
//   iz(k) = izb + k*izs  (D axis, stride 2^14)  -- depends on row i only
//   iy(k) = k*(127/128)  (W axis) -- EXACT in fp32: y0 = k-1, wy0 = k/128
//   ix(k) = ixb + k*ixs  (H axis, stride 1)     -- depends on col j only
//
// Wave shape: 64 lanes = 64 same-row adjacent-j pixels, one k-chunk of 16 per
// wave (512-thread block = 8 k-chunks). Uniform trip counts in a wave; each
// gather touches one contiguous ~65-float x-segment per (z,y) row.
// Each thread splits its valid k-interval (ix,iz in (-1,128)) into
// masked-edge / interior / masked-edge; interior (ix,iz in [1,126),
// conservative vs 1-ulp interval rounding) runs a mask-free, clamp-free body.
// Coprime block swizzle spreads heavy central chunks across CUs; grid is ~2x
// device residency so early-exiting dead blocks get replaced.

#define RES 180
#define JSTRIPS 3                      // ceil(180/64)
#define NCHUNK (4 * RES * JSTRIPS)     // 2160 = 2^4 * 3^3 * 5
#define CHUNK_STRIDE 1013              // prime, coprime to 2160

typedef struct __attribute__((packed, aligned(4))) { float x, y; } f2u;

__global__ __launch_bounds__(512) void proj_kernel(
    const float* __restrict__ vol, const float* __restrict__ poses,
    const float* __restrict__ spacing, float* __restrict__ out) {
  const int tid  = threadIdx.x;
  const int lane = tid & 63;      // adjacent j
  const int ks   = tid >> 6;      // k-chunk 0..7 (16 k each)
  const int chunk = (int)(((long long)blockIdx.x * CHUNK_STRIDE) % NCHUNK);
  const int js = chunk % JSTRIPS;
  const int t  = chunk / JSTRIPS;
  const int i  = t % RES;
  const int b  = t / RES;
  const int j  = js * 64 + lane;
  const bool live = (j < RES);

  const float ex = poses[b * 3 + 0];
  const float ey = poses[b * 3 + 1];
  const float ez = poses[b * 3 + 2];

  const float gx = (float)i - 90.0f;   // lin_x[i]
  const float gy = (float)j - 90.0f;   // lin_y[j]
  const float Ix = gx - ex;
  const float Iy = -ey;                // ~ +300
  const float Iz = gy - ez;

  const float c     = 63.5f / 64.0f;   // 0.9921875 exact
  const float invIy = 1.0f / Iy;

  const float izb = fmaf(ex + Ix, c, 63.5f);
  const float izs = Ix * invIy * c;
  const float ixb = fmaf(ez + Iz, c, 63.5f);
  const float ixs = Iz * invIy * c;

  // ---- valid k-interval (masked correctness): ix,iz in (-1,128) ----
  const int k0 = ks * 16;
  float ka = (float)k0, kb = (float)(k0 + 16);
  if (ixs > 1e-12f)       { ka = fmaxf(ka, (-1.0f - ixb) / ixs); kb = fminf(kb, (128.0f - ixb) / ixs); }
  else if (ixs < -1e-12f) { ka = fmaxf(ka, (128.0f - ixb) / ixs); kb = fminf(kb, (-1.0f - ixb) / ixs); }
  else if (ixb <= -1.0f || ixb >= 128.0f) { kb = ka; }
  if (izs > 1e-12f)       { ka = fmaxf(ka, (-1.0f - izb) / izs); kb = fminf(kb, (128.0f - izb) / izs); }
  else if (izs < -1e-12f) { ka = fmaxf(ka, (128.0f - izb) / izs); kb = fminf(kb, (-1.0f - izb) / izs); }
  else if (izb <= -1.0f || izb >= 128.0f) { kb = ka; }
  ka = fmaxf(ka, (float)k0);
  kb = fminf(kb, (float)(k0 + 16));
  const int kai = (int)ceilf(ka);
  int kbi = (int)ceilf(kb);
  if (!live) kbi = kai;

  // ---- interior sub-interval: ix,iz in [1,126) (1-voxel safety margin) ----
  float ia = ka, ib = kb;
  if (ixs > 1e-12f)       { ia = fmaxf(ia, (1.0f - ixb) / ixs); ib = fminf(ib, (126.0f - ixb) / ixs); }
  else if (ixs < -1e-12f) { ia = fmaxf(ia, (126.0f - ixb) / ixs); ib = fminf(ib, (1.0f - ixb) / ixs); }
  else if (ixb < 1.0f || ixb >= 126.0f) { ib = ia; }
  if (izs > 1e-12f)       { ia = fmaxf(ia, (1.0f - izb) / izs); ib = fminf(ib, (126.0f - izb) / izs); }
  else if (izs < -1e-12f) { ia = fmaxf(ia, (126.0f - izb) / izs); ib = fminf(ib, (1.0f - izb) / izs); }
  else if (izb < 1.0f || izb >= 126.0f) { ib = ia; }
  int m0 = (int)ceilf(fmaxf(ia, 1.0f));   // interior needs k>=1 (y0=k-1)
  int m1 = (int)ceilf(ib);
  m0 = min(max(m0, kai), kbi);
  m1 = min(max(m1, m0), kbi);

  float sum = 0.0f;

  // full masked body (exact reference semantics incl. zero padding)
#define MASKED_BODY(k)                                                         \
  {                                                                            \
    const float kf = (float)(k);                                               \
    const float ix = fmaf(kf, ixs, ixb);                                       \
    const float iy = kf * c;                                                   \
    const float iz = fmaf(kf, izs, izb);                                       \
    const float fx = floorf(ix), fy = floorf(iy), fz = floorf(iz);             \
    const int x0 = (int)fx, y0 = (int)fy, z0 = (int)fz;                        \
    const float wx1 = ix - fx, wy1 = iy - fy, wz1 = iz - fz;                   \
    const float wx0 = 1.0f - wx1, wy0 = 1.0f - wy1, wz0 = 1.0f - wz1;          \
    const float vx0 = ((unsigned)x0       < 128u) ? wx0 : 0.0f;                \
    const float vx1 = ((unsigned)(x0 + 1) < 128u) ? wx1 : 0.0f;                \
    const float vz0 = ((unsigned)z0       < 128u) ? wz0 : 0.0f;                \
    const float vz1 = ((unsigned)(z0 + 1) < 128u) ? wz1 : 0.0f;                \
    const int xb2 = min(max(x0, 0), 126);                                      \
    const bool in = (x0 == xb2);                                               \
    const float wlo = in ? vx0 : vx1;                                          \
    const float whi = in ? vx1 : vx0;                                          \
    const int zc0 = min(max(z0, 0), 127), zc1 = min(max(z0 + 1, 0), 127);      \
    const float* base = vol + ((zc0 << 14) + (y0 << 7) + xb2);                 \
    const int dz = (zc1 - zc0) << 14;                                          \
    const f2u v00 = *(const f2u*)(base);                                       \
    const f2u v01 = *(const f2u*)(base + 128);                                 \
    const f2u v10 = *(const f2u*)(base + dz);                                  \
    const f2u v11 = *(const f2u*)(base + dz + 128);                            \
    const float s00 = fmaf(whi, v00.y, wlo * v00.x);                           \
    const float s01 = fmaf(whi, v01.y, wlo * v01.x);                           \
    const float s10 = fmaf(whi, v10.y, wlo * v10.x);                           \
    const float s11 = fmaf(whi, v11.y, wlo * v11.x);                           \
    const float s0  = fmaf(wy1, s01, wy0 * s00);                               \
    const float s1  = fmaf(wy1, s11, wy0 * s10);                               \
    sum = fmaf(vz0, s0, sum);                                                  \
    sum = fmaf(vz1, s1, sum);                                                  \
  }

  for (int k = kai; k < m0; ++k) MASKED_BODY(k)

#pragma unroll 2
  for (int k = m0; k < m1; ++k) {
    // interior: x0,z0 in [0,126] guaranteed; y0=k-1, wy0=k/128 exact
    const float kf = (float)k;
    const float ix = fmaf(kf, ixs, ixb);
    const float iz = fmaf(kf, izs, izb);
    const float fx = floorf(ix), fz = floorf(iz);
    const int x0 = (int)fx, z0 = (int)fz;
    const float wx1 = ix - fx, wz1 = iz - fz;
    const float wx0 = 1.0f - wx1, wz0 = 1.0f - wz1;
    const float wy0 = kf * 0.0078125f;       // k/128, exact
    const float wy1 = 1.0f - wy0;            // (128-k)/128, exact

    const float* p = vol + ((z0 << 14) + (k << 7) - 128 + x0);  // (z0, k-1, x0)
    const f2u v00 = *(const f2u*)(p);
    const f2u v01 = *(const f2u*)(p + 128);
    const f2u v10 = *(const f2u*)(p + 16384);
    const f2u v11 = *(const f2u*)(p + 16384 + 128);

    const float s00 = fmaf(wx1, v00.y, wx0 * v00.x);
    const float s01 = fmaf(wx1, v01.y, wx0 * v01.x);
    const float s10 = fmaf(wx1, v10.y, wx0 * v10.x);
    const float s11 = fmaf(wx1, v11.y, wx0 * v11.x);
    const float s0  = fmaf(wy1, s01, wy0 * s00);
    const float s1  = fmaf(wy1, s11, wy0 * s10);
    sum = fmaf(wz0, s0, sum);
    sum = fmaf(wz1, s1, sum);
  }

  for (int k = m1; k < kbi; ++k) MASKED_BODY(k)
#undef MASKED_BODY

  __shared__ float part[512];
  part[tid] = sum;
  __syncthreads();

  if (tid < 64 && live) {
    float tot = 0.0f;
#pragma unroll
    for (int s = 0; s < 8; ++s) tot += part[tid + 64 * s];
    const float sxp = spacing[0], syp = spacing[1], szp = spacing[2];
    const float ax = Ix * invIy * sxp;
    const float az = Iz * invIy * szp;
    const float dxl = sqrtf(fmaf(ax, ax, fmaf(az, az, syp * syp)));
    out[((b * RES) + i) * RES + j] = tot * dxl;
  }
}

extern "C" void kernel_launch(void* const* d_in, const int* in_sizes, int n_in,
                              void* d_out, int out_size, void* d_ws, size_t ws_size,
                              hipStream_t stream) {
  const float* vol     = (const float*)d_in[0];   // I_rec [1,1,128,128,128] fp32
  const float* poses   = (const float*)d_in[1];   // [4,3] fp32
  const float* spacing = (const float*)d_in[2];   // [3] fp32
  float* out = (float*)d_out;                     // [4,1,180,180] fp32

  proj_kernel<<<NCHUNK, 512, 0, stream>>>(vol, poses, spacing, out);
}

// Round 7
// 41.054 us; speedup vs baseline: 1.1243x; 1.1243x over previous
//
#include <hip/hip_runtime.h>

// Cone-beam projection: D=W=H=128 volume, 180x180 detector, BATCH=4.
// out[b][0][i][j] = dx(b,i,j) * sum_{k=0..127} trilinear(vol, ray(b,i,j,k))
//
// Index-space ray, linear in k:
//   iz(k) = izb + k*izs  (D axis)   iy(k) = k*(127/128) EXACT (W axis, never OOB)
//   ix(k) = ixb + k*ixs  (H axis)
//
// Main kernel samples a ZERO-PADDED copy of the volume staged in d_ws:
//   pad[z][y][x], z in [0,130), y in [0,128), x in [0,130);
//   pad[z][y][x] = vol[z-1][y][x-1] for z,x in [1,128], else 0.
// OOB corners multiply true zeros == reference's zero padding, so the k-loop
// body has NO masks/clamps/swaps and is wave-uniform.
// Exact y decomposition (round-6 bug was swapping these!):
//   iy = k*127/128 exact; y0 = k-1; frac = 1 - k/128 = weight of row y1=k;
//   k/128 = weight of row y0. Both exact in fp32.
// k=0 reads the y=-1 row times weight 0 (finite garbage, in-slack).
// Front/tail slack = one z-slab + one row + margin each, so 1-ulp k-interval
// rounding (z0=-2 or z0=128) stays inside the allocation; such samples get
// weight ~1e-5 times poison ~3e-13 -> numerically nil.
//
// Wave = 64 same-row adjacent-j pixels x one 16-k chunk (512-thr block);
// per-thread loop covers only its valid k-subinterval; coprime block swizzle
// spreads heavy chunks; grid ~2.1x device residency for refill.

#define RES 180
#define JSTRIPS 3
#define NCHUNK (4 * RES * JSTRIPS)     // 2160
#define CHUNK_STRIDE 1013              // prime, coprime to 2160

#define PH 130                          // padded x extent
#define PW 128                          // y extent (unpadded)
#define PD 130                          // padded z extent
#define PSLAB (PW * PH)                 // 16640 floats per z-slab
#define PAD_ELEMS (PD * PSLAB)          // 2,163,200 floats
#define PAD_FRONT ((size_t)(PSLAB + PH + 128) * 4)   // one slab + row + margin
#define PAD_TAIL  ((size_t)(PSLAB + PH + 128) * 4)
#define WS_NEED (PAD_FRONT + (size_t)PAD_ELEMS * 4 + PAD_TAIL)
#define PAD_OFF_EL (PSLAB + 1)          // +1 z-slab, +1 x  (y origin is 0)

typedef struct __attribute__((packed, aligned(4))) { float x, y; } f2u;

__global__ __launch_bounds__(256) void pad_kernel(
    const float* __restrict__ vol, float* __restrict__ pad) {
  const int t = blockIdx.x * 256 + threadIdx.x;   // index within z-slab
  const int z = blockIdx.y;
  if (t >= PSLAB) return;
  const int y = t / PH;
  const int x = t - y * PH;
  float v = 0.0f;
  if (z >= 1 && z <= 128 && x >= 1 && x <= 128)
    v = vol[(((z - 1)) << 14) + (y << 7) + (x - 1)];
  pad[z * PSLAB + t] = v;
}

__global__ __launch_bounds__(512) void proj_pad_kernel(
    const float* __restrict__ pad, const float* __restrict__ poses,
    const float* __restrict__ spacing, float* __restrict__ out) {
  const int tid  = threadIdx.x;
  const int lane = tid & 63;      // adjacent j
  const int ks   = tid >> 6;      // k-chunk 0..7 (16 k each)
  const int chunk = (int)(((long long)blockIdx.x * CHUNK_STRIDE) % NCHUNK);
  const int js = chunk % JSTRIPS;
  const int t  = chunk / JSTRIPS;
  const int i  = t % RES;
  const int b  = t / RES;
  const int j  = js * 64 + lane;
  const bool live = (j < RES);

  const float ex = poses[b * 3 + 0];
  const float ey = poses[b * 3 + 1];
  const float ez = poses[b * 3 + 2];

  const float gx = (float)i - 90.0f;
  const float gy = (float)j - 90.0f;
  const float Ix = gx - ex;
  const float Iy = -ey;                // ~ +300
  const float Iz = gy - ez;

  const float c     = 63.5f / 64.0f;   // exact
  const float invIy = 1.0f / Iy;

  const float izb = fmaf(ex + Ix, c, 63.5f);
  const float izs = Ix * invIy * c;
  const float ixb = fmaf(ez + Iz, c, 63.5f);
  const float ixs = Iz * invIy * c;

  // valid k-interval: ix,iz in (-1,128), k in [k0, k0+16)
  const int k0 = ks * 16;
  float ka = (float)k0, kb = (float)(k0 + 16);
  if (ixs > 1e-12f)       { ka = fmaxf(ka, (-1.0f - ixb) / ixs); kb = fminf(kb, (128.0f - ixb) / ixs); }
  else if (ixs < -1e-12f) { ka = fmaxf(ka, (128.0f - ixb) / ixs); kb = fminf(kb, (-1.0f - ixb) / ixs); }
  else if (ixb <= -1.0f || ixb >= 128.0f) { kb = ka; }
  if (izs > 1e-12f)       { ka = fmaxf(ka, (-1.0f - izb) / izs); kb = fminf(kb, (128.0f - izb) / izs); }
  else if (izs < -1e-12f) { ka = fmaxf(ka, (128.0f - izb) / izs); kb = fminf(kb, (-1.0f - izb) / izs); }
  else if (izb <= -1.0f || izb >= 128.0f) { kb = ka; }
  ka = fmaxf(ka, (float)k0);
  kb = fminf(kb, (float)(k0 + 16));
  const int kai = (int)ceilf(ka);
  int kbi = (int)ceilf(kb);
  if (!live) kbi = kai;

  const float* pbase = pad + PAD_OFF_EL;   // padded origin

  float sum = 0.0f;
#pragma unroll 2
  for (int k = kai; k < kbi; ++k) {
    const float kf = (float)k;
    const float ix = fmaf(kf, ixs, ixb);
    const float iz = fmaf(kf, izs, izb);
    const float fx = floorf(ix), fz = floorf(iz);
    const int x0 = (int)fx, z0 = (int)fz;
    const float wx1 = ix - fx, wz1 = iz - fz;
    const float wx0 = 1.0f - wx1, wz0 = 1.0f - wz1;
    const float wyA = kf * 0.0078125f;   // k/128 exact  = weight of row y0=k-1
    const float wyB = 1.0f - wyA;        // 1-k/128 exact = weight of row y1=k

    // padded addr: (z0+1)*PSLAB + (k-1)*PH + (x0+1), origin folded into pbase
    const float* p = pbase + (z0 * PSLAB + (k - 1) * PH + x0);
    const f2u v00 = *(const f2u*)(p);              // (z0,   y0)
    const f2u v01 = *(const f2u*)(p + PH);         // (z0,   y1)
    const f2u v10 = *(const f2u*)(p + PSLAB);      // (z0+1, y0)
    const f2u v11 = *(const f2u*)(p + PSLAB + PH); // (z0+1, y1)

    const float s00 = fmaf(wx1, v00.y, wx0 * v00.x);
    const float s01 = fmaf(wx1, v01.y, wx0 * v01.x);
    const float s10 = fmaf(wx1, v10.y, wx0 * v10.x);
    const float s11 = fmaf(wx1, v11.y, wx0 * v11.x);
    const float s0  = fmaf(wyB, s01, wyA * s00);   // y0 row * k/128 + y1 row * (1-k/128)
    const float s1  = fmaf(wyB, s11, wyA * s10);
    sum = fmaf(wz0, s0, sum);
    sum = fmaf(wz1, s1, sum);
  }

  __shared__ float part[512];
  part[tid] = sum;
  __syncthreads();

  if (tid < 64 && live) {
    float tot = 0.0f;
#pragma unroll
    for (int s = 0; s < 8; ++s) tot += part[tid + 64 * s];
    const float sxp = spacing[0], syp = spacing[1], szp = spacing[2];
    const float ax = Ix * invIy * sxp;
    const float az = Iz * invIy * szp;
    const float dxl = sqrtf(fmaf(ax, ax, fmaf(az, az, syp * syp)));
    out[((b * RES) + i) * RES + j] = tot * dxl;
  }
}

// ---- fallback (round-4 proven kernel) if ws is too small for the pad ----
#define F_PPB 32
#define F_NCHUNK (4 * RES * RES / F_PPB)   // 4050
__global__ __launch_bounds__(256) void proj_masked_kernel(
    const float* __restrict__ vol, const float* __restrict__ poses,
    const float* __restrict__ spacing, float* __restrict__ out) {
  const int tid = threadIdx.x;
  const int lp  = tid & 31;
  const int ks  = tid >> 5;
  const int chunk = (int)(((long long)blockIdx.x * 1013) % F_NCHUNK);
  const int gpix = chunk * F_PPB + lp;
  const int b   = gpix / (RES * RES);
  const int rem = gpix - b * (RES * RES);
  const int i   = rem / RES;
  const int j   = rem - i * RES;
  const float ex = poses[b * 3 + 0], ey = poses[b * 3 + 1], ez = poses[b * 3 + 2];
  const float gx = (float)i - 90.0f, gy = (float)j - 90.0f;
  const float Ix = gx - ex, Iy = -ey, Iz = gy - ez;
  const float c = 63.5f / 64.0f, invIy = 1.0f / Iy;
  const float izb = fmaf(ex + Ix, c, 63.5f), izs = Ix * invIy * c;
  const float ixb = fmaf(ez + Iz, c, 63.5f), ixs = Iz * invIy * c;
  const int k0 = ks * 16;
  float ka = (float)k0, kb = (float)(k0 + 16);
  if (ixs > 1e-12f)       { ka = fmaxf(ka, (-1.0f - ixb) / ixs); kb = fminf(kb, (128.0f - ixb) / ixs); }
  else if (ixs < -1e-12f) { ka = fmaxf(ka, (128.0f - ixb) / ixs); kb = fminf(kb, (-1.0f - ixb) / ixs); }
  else if (ixb <= -1.0f || ixb >= 128.0f) { kb = ka; }
  if (izs > 1e-12f)       { ka = fmaxf(ka, (-1.0f - izb) / izs); kb = fminf(kb, (128.0f - izb) / izs); }
  else if (izs < -1e-12f) { ka = fmaxf(ka, (128.0f - izb) / izs); kb = fminf(kb, (-1.0f - izb) / izs); }
  else if (izb <= -1.0f || izb >= 128.0f) { kb = ka; }
  ka = fmaxf(ka, (float)k0); kb = fminf(kb, (float)(k0 + 16));
  const int kai = (int)ceilf(ka);
  const int kbi = (int)ceilf(kb);
  float sum = 0.0f;
#pragma unroll 2
  for (int k = kai; k < kbi; ++k) {
    const float kf = (float)k;
    const float ix = fmaf(kf, ixs, ixb);
    const float iy = kf * c;
    const float iz = fmaf(kf, izs, izb);
    const float fx = floorf(ix), fy = floorf(iy), fz = floorf(iz);
    const int x0 = (int)fx, y0 = (int)fy, z0 = (int)fz;
    const float wx1 = ix - fx, wy1 = iy - fy, wz1 = iz - fz;
    const float wx0 = 1.0f - wx1, wy0 = 1.0f - wy1, wz0 = 1.0f - wz1;
    const float vx0 = ((unsigned)x0       < 128u) ? wx0 : 0.0f;
    const float vx1 = ((unsigned)(x0 + 1) < 128u) ? wx1 : 0.0f;
    const float vz0 = ((unsigned)z0       < 128u) ? wz0 : 0.0f;
    const float vz1 = ((unsigned)(z0 + 1) < 128u) ? wz1 : 0.0f;
    const int xb2 = min(max(x0, 0), 126);
    const bool in = (x0 == xb2);
    const float wlo = in ? vx0 : vx1;
    const float whi = in ? vx1 : vx0;
    const int zc0 = min(max(z0, 0), 127), zc1 = min(max(z0 + 1, 0), 127);
    const float* base = vol + ((zc0 << 14) + (y0 << 7) + xb2);
    const int dz = (zc1 - zc0) << 14;
    const f2u v00 = *(const f2u*)(base);
    const f2u v01 = *(const f2u*)(base + 128);
    const f2u v10 = *(const f2u*)(base + dz);
    const f2u v11 = *(const f2u*)(base + dz + 128);
    const float s00 = fmaf(whi, v00.y, wlo * v00.x);
    const float s01 = fmaf(whi, v01.y, wlo * v01.x);
    const float s10 = fmaf(whi, v10.y, wlo * v10.x);
    const float s11 = fmaf(whi, v11.y, wlo * v11.x);
    const float s0  = fmaf(wy1, s01, wy0 * s00);
    const float s1  = fmaf(wy1, s11, wy0 * s10);
    sum = fmaf(vz0, s0, sum);
    sum = fmaf(vz1, s1, sum);
  }
  __shared__ float part[256];
  part[tid] = sum;
  __syncthreads();
  if (tid < F_PPB) {
    float tot = 0.0f;
#pragma unroll
    for (int s = 0; s < 8; ++s) tot += part[tid + 32 * s];
    const float sxp = spacing[0], syp = spacing[1], szp = spacing[2];
    const float ax = Ix * invIy * sxp;
    const float az = Iz * invIy * szp;
    const float dxl = sqrtf(fmaf(ax, ax, fmaf(az, az, syp * syp)));
    out[gpix] = tot * dxl;
  }
}

extern "C" void kernel_launch(void* const* d_in, const int* in_sizes, int n_in,
                              void* d_out, int out_size, void* d_ws, size_t ws_size,
                              hipStream_t stream) {
  const float* vol     = (const float*)d_in[0];
  const float* poses   = (const float*)d_in[1];
  const float* spacing = (const float*)d_in[2];
  float* out = (float*)d_out;

  if (ws_size >= WS_NEED) {
    float* pad = (float*)((char*)d_ws + PAD_FRONT);
    dim3 pg((PSLAB + 255) / 256, PD);
    pad_kernel<<<pg, 256, 0, stream>>>(vol, pad);
    proj_pad_kernel<<<NCHUNK, 512, 0, stream>>>(pad, poses, spacing, out);
  } else {
    proj_masked_kernel<<<F_NCHUNK * 2, 256, 0, stream>>>(vol, poses, spacing, out);
  }
}

// Round 8
// 36.493 us; speedup vs baseline: 1.2648x; 1.1250x over previous
//
#include <hip/hip_runtime.h>

// Cone-beam projection: D=W=H=128 volume, 180x180 detector, BATCH=4.
// out[b][0][i][j] = dx(b,i,j) * sum_{k=0..127} trilinear(vol, ray(b,i,j,k))
//
// Index-space ray, linear in k:
//   iz(k) = izb + k*izs  (D axis)   iy(k) = k*(127/128) EXACT (W axis, never OOB)
//   ix(k) = ixb + k*ixs  (H axis)
//
// Stage a ZERO-PADDED volume in d_ws: pad[z][y][x], z,x in [0,130), y in
// [0,128); pad[z][y][x] = vol[z-1][y][x-1] for z,x in [1,128], else 0.
// OOB corners multiply true zeros == reference zero padding -> the k-loop
// body has NO masks/clamps/swaps and is wave-uniform.
// Exact y split: y0 = k-1; weight(y0) = k/128, weight(y1=k) = 1-k/128 (exact).
// k=0 reads the y=-1 row times weight 0 (finite garbage, inside front slack).
// Front/tail slack = one z-slab + row + margin so 1-ulp interval rounding
// (z0=-2 / z0=128) stays in-allocation (weights there ~1e-5 * ~1e-13 poison).
//
// SHAPE (round-4 proven; rounds 5/7 proved 64j/512-thr blocks regress ~1.5x):
// 256-thr blocks = 32 adjacent-j pixels x 8 k-chunks of 16; wave = 32 px x 2
// chunks; LDS-reduce 8 partials/pixel; 4050 blocks (~2x residency refill);
// coprime swizzle spreads heavy central chunks across CUs.

#define RES 180
#define PPB 32
#define NCHUNK (4 * RES * RES / PPB)   // 4050
#define CHUNK_STRIDE 1013              // prime, coprime to 4050

#define PH 130                          // padded x extent
#define PW 128                          // y extent (unpadded)
#define PD 130                          // padded z extent
#define PSLAB (PW * PH)                 // 16640 floats per z-slab
#define PAD_ELEMS (PD * PSLAB)          // 2,163,200 floats
#define PAD_FRONT ((size_t)(PSLAB + PH + 128) * 4)
#define PAD_TAIL  ((size_t)(PSLAB + PH + 128) * 4)
#define WS_NEED (PAD_FRONT + (size_t)PAD_ELEMS * 4 + PAD_TAIL)
#define PAD_OFF_EL (PSLAB + 1)          // +1 z-slab, +1 x (y origin 0)

typedef struct __attribute__((packed, aligned(4))) { float x, y; } f2u;

__global__ __launch_bounds__(256) void pad_kernel(
    const float* __restrict__ vol, float* __restrict__ pad) {
  const int t = blockIdx.x * 256 + threadIdx.x;   // index within z-slab
  const int z = blockIdx.y;
  if (t >= PSLAB) return;
  const int y = t / PH;
  const int x = t - y * PH;
  float v = 0.0f;
  if (z >= 1 && z <= 128 && x >= 1 && x <= 128)
    v = vol[(((z - 1)) << 14) + (y << 7) + (x - 1)];
  pad[z * PSLAB + t] = v;
}

__global__ __launch_bounds__(256) void proj_pad_kernel(
    const float* __restrict__ pad, const float* __restrict__ poses,
    const float* __restrict__ spacing, float* __restrict__ out) {
  const int tid = threadIdx.x;
  const int lp  = tid & 31;       // pixel slot
  const int ks  = tid >> 5;       // k-chunk 0..7 (16 k each)
  const int chunk = (int)(((long long)blockIdx.x * CHUNK_STRIDE) % NCHUNK);
  const int gpix = chunk * PPB + lp;

  const int b   = gpix / (RES * RES);
  const int rem = gpix - b * (RES * RES);
  const int i   = rem / RES;
  const int j   = rem - i * RES;

  const float ex = poses[b * 3 + 0];
  const float ey = poses[b * 3 + 1];
  const float ez = poses[b * 3 + 2];

  const float gx = (float)i - 90.0f;
  const float gy = (float)j - 90.0f;
  const float Ix = gx - ex;
  const float Iy = -ey;                // ~ +300
  const float Iz = gy - ez;

  const float c     = 63.5f / 64.0f;   // exact
  const float invIy = 1.0f / Iy;

  const float izb = fmaf(ex + Ix, c, 63.5f);
  const float izs = Ix * invIy * c;
  const float ixb = fmaf(ez + Iz, c, 63.5f);
  const float ixs = Iz * invIy * c;

  // valid k-interval: ix,iz in (-1,128), k in [k0, k0+16)
  const int k0 = ks * 16;
  float ka = (float)k0, kb = (float)(k0 + 16);
  if (ixs > 1e-12f)       { ka = fmaxf(ka, (-1.0f - ixb) / ixs); kb = fminf(kb, (128.0f - ixb) / ixs); }
  else if (ixs < -1e-12f) { ka = fmaxf(ka, (128.0f - ixb) / ixs); kb = fminf(kb, (-1.0f - ixb) / ixs); }
  else if (ixb <= -1.0f || ixb >= 128.0f) { kb = ka; }
  if (izs > 1e-12f)       { ka = fmaxf(ka, (-1.0f - izb) / izs); kb = fminf(kb, (128.0f - izb) / izs); }
  else if (izs < -1e-12f) { ka = fmaxf(ka, (128.0f - izb) / izs); kb = fminf(kb, (-1.0f - izb) / izs); }
  else if (izb <= -1.0f || izb >= 128.0f) { kb = ka; }
  ka = fmaxf(ka, (float)k0);
  kb = fminf(kb, (float)(k0 + 16));
  const int kai = (int)ceilf(ka);
  const int kbi = (int)ceilf(kb);

  const float* pbase = pad + PAD_OFF_EL;   // padded origin

  float sum = 0.0f;
#pragma unroll 2
  for (int k = kai; k < kbi; ++k) {
    const float kf = (float)k;
    const float ix = fmaf(kf, ixs, ixb);
    const float iz = fmaf(kf, izs, izb);
    const float fx = floorf(ix), fz = floorf(iz);
    const int x0 = (int)fx, z0 = (int)fz;
    const float wx1 = ix - fx, wz1 = iz - fz;
    const float wx0 = 1.0f - wx1, wz0 = 1.0f - wz1;
    const float wyA = kf * 0.0078125f;   // k/128 exact  = weight of row y0=k-1
    const float wyB = 1.0f - wyA;        // 1-k/128 exact = weight of row y1=k

    // padded addr: (z0+1)*PSLAB + (k-1)*PH + (x0+1), origin folded into pbase
    const float* p = pbase + (z0 * PSLAB + (k - 1) * PH + x0);
    const f2u v00 = *(const f2u*)(p);              // (z0,   y0)
    const f2u v01 = *(const f2u*)(p + PH);         // (z0,   y1)
    const f2u v10 = *(const f2u*)(p + PSLAB);      // (z0+1, y0)
    const f2u v11 = *(const f2u*)(p + PSLAB + PH); // (z0+1, y1)

    const float s00 = fmaf(wx1, v00.y, wx0 * v00.x);
    const float s01 = fmaf(wx1, v01.y, wx0 * v01.x);
    const float s10 = fmaf(wx1, v10.y, wx0 * v10.x);
    const float s11 = fmaf(wx1, v11.y, wx0 * v11.x);
    const float s0  = fmaf(wyB, s01, wyA * s00);
    const float s1  = fmaf(wyB, s11, wyA * s10);
    sum = fmaf(wz0, s0, sum);
    sum = fmaf(wz1, s1, sum);
  }

  __shared__ float part[256];
  part[tid] = sum;
  __syncthreads();

  if (tid < PPB) {
    float tot = 0.0f;
#pragma unroll
    for (int s = 0; s < 8; ++s) tot += part[tid + 32 * s];
    const float sxp = spacing[0], syp = spacing[1], szp = spacing[2];
    const float ax = Ix * invIy * sxp;
    const float az = Iz * invIy * szp;
    const float dxl = sqrtf(fmaf(ax, ax, fmaf(az, az, syp * syp)));
    out[gpix] = tot * dxl;
  }
}

// ---- fallback (round-4 proven masked kernel) if ws too small for the pad ----
__global__ __launch_bounds__(256) void proj_masked_kernel(
    const float* __restrict__ vol, const float* __restrict__ poses,
    const float* __restrict__ spacing, float* __restrict__ out) {
  const int tid = threadIdx.x;
  const int lp  = tid & 31;
  const int ks  = tid >> 5;
  const int chunk = (int)(((long long)blockIdx.x * CHUNK_STRIDE) % NCHUNK);
  const int gpix = chunk * PPB + lp;
  const int b   = gpix / (RES * RES);
  const int rem = gpix - b * (RES * RES);
  const int i   = rem / RES;
  const int j   = rem - i * RES;
  const float ex = poses[b * 3 + 0], ey = poses[b * 3 + 1], ez = poses[b * 3 + 2];
  const float gx = (float)i - 90.0f, gy = (float)j - 90.0f;
  const float Ix = gx - ex, Iy = -ey, Iz = gy - ez;
  const float c = 63.5f / 64.0f, invIy = 1.0f / Iy;
  const float izb = fmaf(ex + Ix, c, 63.5f), izs = Ix * invIy * c;
  const float ixb = fmaf(ez + Iz, c, 63.5f), ixs = Iz * invIy * c;
  const int k0 = ks * 16;
  float ka = (float)k0, kb = (float)(k0 + 16);
  if (ixs > 1e-12f)       { ka = fmaxf(ka, (-1.0f - ixb) / ixs); kb = fminf(kb, (128.0f - ixb) / ixs); }
  else if (ixs < -1e-12f) { ka = fmaxf(ka, (128.0f - ixb) / ixs); kb = fminf(kb, (-1.0f - ixb) / ixs); }
  else if (ixb <= -1.0f || ixb >= 128.0f) { kb = ka; }
  if (izs > 1e-12f)       { ka = fmaxf(ka, (-1.0f - izb) / izs); kb = fminf(kb, (128.0f - izb) / izs); }
  else if (izs < -1e-12f) { ka = fmaxf(ka, (128.0f - izb) / izs); kb = fminf(kb, (-1.0f - izb) / izs); }
  else if (izb <= -1.0f || izb >= 128.0f) { kb = ka; }
  ka = fmaxf(ka, (float)k0); kb = fminf(kb, (float)(k0 + 16));
  const int kai = (int)ceilf(ka);
  const int kbi = (int)ceilf(kb);
  float sum = 0.0f;
#pragma unroll 2
  for (int k = kai; k < kbi; ++k) {
    const float kf = (float)k;
    const float ix = fmaf(kf, ixs, ixb);
    const float iy = kf * c;
    const float iz = fmaf(kf, izs, izb);
    const float fx = floorf(ix), fy = floorf(iy), fz = floorf(iz);
    const int x0 = (int)fx, y0 = (int)fy, z0 = (int)fz;
    const float wx1 = ix - fx, wy1 = iy - fy, wz1 = iz - fz;
    const float wx0 = 1.0f - wx1, wy0 = 1.0f - wy1, wz0 = 1.0f - wz1;
    const float vx0 = ((unsigned)x0       < 128u) ? wx0 : 0.0f;
    const float vx1 = ((unsigned)(x0 + 1) < 128u) ? wx1 : 0.0f;
    const float vz0 = ((unsigned)z0       < 128u) ? wz0 : 0.0f;
    const float vz1 = ((unsigned)(z0 + 1) < 128u) ? wz1 : 0.0f;
    const int xb2 = min(max(x0, 0), 126);
    const bool in = (x0 == xb2);
    const float wlo = in ? vx0 : vx1;
    const float whi = in ? vx1 : vx0;
    const int zc0 = min(max(z0, 0), 127), zc1 = min(max(z0 + 1, 0), 127);
    const float* base = vol + ((zc0 << 14) + (y0 << 7) + xb2);
    const int dz = (zc1 - zc0) << 14;
    const f2u v00 = *(const f2u*)(base);
    const f2u v01 = *(const f2u*)(base + 128);
    const f2u v10 = *(const f2u*)(base + dz);
    const f2u v11 = *(const f2u*)(base + dz + 128);
    const float s00 = fmaf(whi, v00.y, wlo * v00.x);
    const float s01 = fmaf(whi, v01.y, wlo * v01.x);
    const float s10 = fmaf(whi, v10.y, wlo * v10.x);
    const float s11 = fmaf(whi, v11.y, wlo * v11.x);
    const float s0  = fmaf(wy1, s01, wy0 * s00);
    const float s1  = fmaf(wy1, s11, wy0 * s10);
    sum = fmaf(vz0, s0, sum);
    sum = fmaf(vz1, s1, sum);
  }
  __shared__ float part[256];
  part[tid] = sum;
  __syncthreads();
  if (tid < PPB) {
    float tot = 0.0f;
#pragma unroll
    for (int s = 0; s < 8; ++s) tot += part[tid + 32 * s];
    const float sxp = spacing[0], syp = spacing[1], szp = spacing[2];
    const float ax = Ix * invIy * sxp;
    const float az = Iz * invIy * szp;
    const float dxl = sqrtf(fmaf(ax, ax, fmaf(az, az, syp * syp)));
    out[gpix] = tot * dxl;
  }
}

extern "C" void kernel_launch(void* const* d_in, const int* in_sizes, int n_in,
                              void* d_out, int out_size, void* d_ws, size_t ws_size,
                              hipStream_t stream) {
  const float* vol     = (const float*)d_in[0];
  const float* poses   = (const float*)d_in[1];
  const float* spacing = (const float*)d_in[2];
  float* out = (float*)d_out;

  if (ws_size >= WS_NEED) {
    float* pad = (float*)((char*)d_ws + PAD_FRONT);
    dim3 pg((PSLAB + 255) / 256, PD);
    pad_kernel<<<pg, 256, 0, stream>>>(vol, pad);
    proj_pad_kernel<<<NCHUNK, 256, 0, stream>>>(pad, poses, spacing, out);
  } else {
    proj_masked_kernel<<<NCHUNK, 256, 0, stream>>>(vol, poses, spacing, out);
  }
}

// Round 9
// 34.553 us; speedup vs baseline: 1.3358x; 1.0562x over previous
//
#include <hip/hip_runtime.h>

// Cone-beam projection: D=W=H=128 volume, 180x180 detector, BATCH=4.
// out[b][0][i][j] = dx(b,i,j) * sum_{k=0..127} trilinear(vol, ray(b,i,j,k))
//
// Index-space ray, linear in k:
//   iz(k) = izb + k*izs (D axis, stride 2^14)
//   iy(k) = k*(127/128) EXACT -> rows (k-1, k), weights (k/128, 1-k/128) exact
//   ix(k) = ixb + k*ixs (H axis, stride 1)
//
// ROUND-8 LESSON: per-call staging (pad rewrite) dirties L2 every replay and
// forces kernel-boundary flushes -> read the ORIGINAL read-only vol (stays
// warm in L2 across graph replays) with masked borders.
//
// STRUCTURE: k-partitioned across XCDs. Block bid: g = bid&7 (HW round-robins
// blocks over 8 XCDs) owns k in [16g,16g+16); pixel-block pb = bid>>3 covers
// 256 adjacent pixels. Each XCD then only touches vol y-slab [16g-1,16g+16]
// ~= 1.2 MB -> fully L2-resident gathers (vs 8MB/XCD thrash with the old
// swizzle). Per-pixel partials go to d_ws[8][NPIX]; a tiny reduce kernel
// sums 8 and applies dx (deterministic, no atomics).
//
// Wave = 64 adjacent same-k pixels -> near-identical k-intervals, so interior
// bounds are WAVE-REDUCED (shfl min/max; round-5's per-lane split regressed):
// [m0w,m1w) = intersection of lane interiors runs a mask/clamp-free body;
// edges run the fully-masked body under per-lane guards. Ranges partition
// [kaiw,kbiw) exactly -> zero duplicated trips.

#define RES 180
#define NPIX (4 * RES * RES)       // 129600
#define PB_N 507                   // ceil(NPIX/256)
#define PB_STRIDE 251              // prime, coprime to 507 = 3*13^2
#define NG 8
#define BIG (1 << 29)

typedef struct __attribute__((packed, aligned(4))) { float x, y; } f2u;

__global__ __launch_bounds__(256) void proj_part_kernel(
    const float* __restrict__ vol, const float* __restrict__ poses,
    float* __restrict__ part) {
  const int g  = blockIdx.x & 7;                       // k-group -> XCD
  const int pb = (int)(((blockIdx.x >> 3) * PB_STRIDE) % PB_N);
  const int gpix = pb * 256 + threadIdx.x;
  const bool live = (gpix < NPIX);
  const int gp  = live ? gpix : (NPIX - 1);

  const int b   = gp / (RES * RES);
  const int rem = gp - b * (RES * RES);
  const int i   = rem / RES;
  const int j   = rem - i * RES;

  const float ex = poses[b * 3 + 0];
  const float ey = poses[b * 3 + 1];
  const float ez = poses[b * 3 + 2];

  const float Ix = ((float)i - 90.0f) - ex;
  const float Iy = -ey;                // ~ +300
  const float Iz = ((float)j - 90.0f) - ez;

  const float c     = 63.5f / 64.0f;   // exact
  const float invIy = 1.0f / Iy;

  const float izb = fmaf(ex + Ix, c, 63.5f);
  const float izs = Ix * invIy * c;
  const float ixb = fmaf(ez + Iz, c, 63.5f);
  const float ixs = Iz * invIy * c;

  // ---- valid k-interval: ix,iz in (-1,128), k in [k0,k0+16) ----
  const int k0 = g * 16;
  float ka = (float)k0, kb = (float)(k0 + 16);
  if (ixs > 1e-12f)       { ka = fmaxf(ka, (-1.0f - ixb) / ixs); kb = fminf(kb, (128.0f - ixb) / ixs); }
  else if (ixs < -1e-12f) { ka = fmaxf(ka, (128.0f - ixb) / ixs); kb = fminf(kb, (-1.0f - ixb) / ixs); }
  else if (ixb <= -1.0f || ixb >= 128.0f) { kb = ka; }
  if (izs > 1e-12f)       { ka = fmaxf(ka, (-1.0f - izb) / izs); kb = fminf(kb, (128.0f - izb) / izs); }
  else if (izs < -1e-12f) { ka = fmaxf(ka, (128.0f - izb) / izs); kb = fminf(kb, (-1.0f - izb) / izs); }
  else if (izb <= -1.0f || izb >= 128.0f) { kb = ka; }
  ka = fmaxf(ka, (float)k0);
  kb = fminf(kb, (float)(k0 + 16));
  int kai = (int)ceilf(ka);
  int kbi = (int)ceilf(kb);
  if (!live) kbi = kai;
  const bool valid = (kbi > kai);

  // ---- interior: ix,iz in [1,126) (1-voxel margin vs rounding) ----
  float ia = ka, ib = kb;
  if (ixs > 1e-12f)       { ia = fmaxf(ia, (1.0f - ixb) / ixs); ib = fminf(ib, (126.0f - ixb) / ixs); }
  else if (ixs < -1e-12f) { ia = fmaxf(ia, (126.0f - ixb) / ixs); ib = fminf(ib, (1.0f - ixb) / ixs); }
  else if (ixb < 1.0f || ixb >= 126.0f) { ib = ia; }
  if (izs > 1e-12f)       { ia = fmaxf(ia, (1.0f - izb) / izs); ib = fminf(ib, (126.0f - izb) / izs); }
  else if (izs < -1e-12f) { ia = fmaxf(ia, (126.0f - izb) / izs); ib = fminf(ib, (1.0f - izb) / izs); }
  else if (izb < 1.0f || izb >= 126.0f) { ib = ia; }
  int m0 = min(max((int)ceilf(ia), kai), kbi);
  int m1 = min(max((int)ceilf(ib), m0), kbi);
  const bool hasInt = valid && (m1 > m0);

  // ---- wave-uniform bounds (neutral sentinels for dead/no-interior lanes) ----
  int kaiw = valid ? kai : BIG;
  int kbiw = valid ? kbi : -BIG;
  int m0w  = hasInt ? m0 : BIG;
  int m1w  = hasInt ? m1 : BIG;
#pragma unroll
  for (int m = 32; m >= 1; m >>= 1) {
    kaiw = min(kaiw, __shfl_xor(kaiw, m));
    kbiw = max(kbiw, __shfl_xor(kbiw, m));
    m0w  = max(m0w,  __shfl_xor(m0w,  m));
    m1w  = min(m1w,  __shfl_xor(m1w,  m));
  }
  m0w = min(max(m0w, kaiw), kbiw);
  m1w = min(max(m1w, m0w), kbiw);

  float sum = 0.0f;

#define MASKED_BODY(k)                                                         \
  if (k >= kai && k < kbi) {                                                   \
    const float kf = (float)(k);                                               \
    const float ix = fmaf(kf, ixs, ixb);                                       \
    const float iz = fmaf(kf, izs, izb);                                       \
    const float fx = floorf(ix), fz = floorf(iz);                              \
    const int x0 = (int)fx, z0 = (int)fz;                                      \
    const float wx1 = ix - fx, wz1 = iz - fz;                                  \
    const float wx0 = 1.0f - wx1, wz0 = 1.0f - wz1;                            \
    const float wyA = kf * 0.0078125f;  /* weight of row k-1, exact */         \
    const float wyB = 1.0f - wyA;       /* weight of row k, exact */           \
    const int yoffA = max((k) - 1, 0) << 7;                                    \
    const int yoffB = (k) << 7;                                                \
    const float vx0 = ((unsigned)x0       < 128u) ? wx0 : 0.0f;                \
    const float vx1 = ((unsigned)(x0 + 1) < 128u) ? wx1 : 0.0f;                \
    const float vz0 = ((unsigned)z0       < 128u) ? wz0 : 0.0f;                \
    const float vz1 = ((unsigned)(z0 + 1) < 128u) ? wz1 : 0.0f;                \
    const int xb2 = min(max(x0, 0), 126);                                      \
    const bool inx = (x0 == xb2);                                              \
    const float wlo = inx ? vx0 : vx1;                                         \
    const float whi = inx ? vx1 : vx0;                                         \
    const int zc0 = min(max(z0, 0), 127), zc1 = min(max(z0 + 1, 0), 127);      \
    const float* base = vol + ((zc0 << 14) + xb2);                             \
    const int dz = (zc1 - zc0) << 14;                                          \
    const f2u v00 = *(const f2u*)(base + yoffA);                               \
    const f2u v01 = *(const f2u*)(base + yoffB);                               \
    const f2u v10 = *(const f2u*)(base + dz + yoffA);                          \
    const f2u v11 = *(const f2u*)(base + dz + yoffB);                          \
    const float s00 = fmaf(whi, v00.y, wlo * v00.x);                           \
    const float s01 = fmaf(whi, v01.y, wlo * v01.x);                           \
    const float s10 = fmaf(whi, v10.y, wlo * v10.x);                           \
    const float s11 = fmaf(whi, v11.y, wlo * v11.x);                           \
    const float s0  = fmaf(wyB, s01, wyA * s00);                               \
    const float s1  = fmaf(wyB, s11, wyA * s10);                               \
    sum = fmaf(vz0, s0, sum);                                                  \
    sum = fmaf(vz1, s1, sum);                                                  \
  }

  for (int k = kaiw; k < m0w; ++k) MASKED_BODY(k)

  // interior: every lane is inside its own [m0,m1) by construction (m0w =
  // wave-max m0, m1w = wave-min m1) -> no guards, no masks, no clamps.
#pragma unroll 2
  for (int k = m0w; k < m1w; ++k) {
    const float kf = (float)k;
    const float ix = fmaf(kf, ixs, ixb);
    const float iz = fmaf(kf, izs, izb);
    const float fx = floorf(ix), fz = floorf(iz);
    const int x0 = (int)fx, z0 = (int)fz;        // both in [0,126]
    const float wx1 = ix - fx, wz1 = iz - fz;
    const float wx0 = 1.0f - wx1, wz0 = 1.0f - wz1;
    const float wyA = kf * 0.0078125f;
    const float wyB = 1.0f - wyA;
    const int yoffA = max(k - 1, 0) << 7;        // wave-uniform
    const int yoffB = k << 7;

    const float* p0 = vol + ((z0 << 14) + x0);
    const f2u v00 = *(const f2u*)(p0 + yoffA);
    const f2u v01 = *(const f2u*)(p0 + yoffB);
    const f2u v10 = *(const f2u*)(p0 + 16384 + yoffA);
    const f2u v11 = *(const f2u*)(p0 + 16384 + yoffB);

    const float s00 = fmaf(wx1, v00.y, wx0 * v00.x);
    const float s01 = fmaf(wx1, v01.y, wx0 * v01.x);
    const float s10 = fmaf(wx1, v10.y, wx0 * v10.x);
    const float s11 = fmaf(wx1, v11.y, wx0 * v11.x);
    const float s0  = fmaf(wyB, s01, wyA * s00);
    const float s1  = fmaf(wyB, s11, wyA * s10);
    sum = fmaf(wz0, s0, sum);
    sum = fmaf(wz1, s1, sum);
  }

  for (int k = m1w; k < kbiw; ++k) MASKED_BODY(k)
#undef MASKED_BODY

  if (live) part[g * NPIX + gpix] = sum;
}

__global__ __launch_bounds__(256) void reduce_kernel(
    const float* __restrict__ part, const float* __restrict__ poses,
    const float* __restrict__ spacing, float* __restrict__ out) {
  const int p = blockIdx.x * 256 + threadIdx.x;
  if (p >= NPIX) return;
  float s = 0.0f;
#pragma unroll
  for (int g = 0; g < NG; ++g) s += part[g * NPIX + p];

  const int b   = p / (RES * RES);
  const int rem = p - b * (RES * RES);
  const int i   = rem / RES;
  const int j   = rem - i * RES;
  const float ex = poses[b * 3 + 0];
  const float ey = poses[b * 3 + 1];
  const float ez = poses[b * 3 + 2];
  const float Ix = ((float)i - 90.0f) - ex;
  const float Iz = ((float)j - 90.0f) - ez;
  const float invIy = 1.0f / (-ey);
  const float ax = Ix * invIy * spacing[0];
  const float az = Iz * invIy * spacing[2];
  const float sy = spacing[1];
  out[p] = s * sqrtf(fmaf(ax, ax, fmaf(az, az, sy * sy)));
}

// ---- fallback (round-4 proven single-kernel) if ws too small ----
#define F_PPB 32
#define F_NCHUNK (NPIX / F_PPB)   // 4050
__global__ __launch_bounds__(256) void proj_masked_kernel(
    const float* __restrict__ vol, const float* __restrict__ poses,
    const float* __restrict__ spacing, float* __restrict__ out) {
  const int tid = threadIdx.x;
  const int lp  = tid & 31;
  const int ks  = tid >> 5;
  const int chunk = (int)(((long long)blockIdx.x * 1013) % F_NCHUNK);
  const int gpix = chunk * F_PPB + lp;
  const int b   = gpix / (RES * RES);
  const int rem = gpix - b * (RES * RES);
  const int i   = rem / RES;
  const int j   = rem - i * RES;
  const float ex = poses[b * 3 + 0], ey = poses[b * 3 + 1], ez = poses[b * 3 + 2];
  const float Ix = ((float)i - 90.0f) - ex, Iy = -ey, Iz = ((float)j - 90.0f) - ez;
  const float c = 63.5f / 64.0f, invIy = 1.0f / Iy;
  const float izb = fmaf(ex + Ix, c, 63.5f), izs = Ix * invIy * c;
  const float ixb = fmaf(ez + Iz, c, 63.5f), ixs = Iz * invIy * c;
  const int k0 = ks * 16;
  float ka = (float)k0, kb = (float)(k0 + 16);
  if (ixs > 1e-12f)       { ka = fmaxf(ka, (-1.0f - ixb) / ixs); kb = fminf(kb, (128.0f - ixb) / ixs); }
  else if (ixs < -1e-12f) { ka = fmaxf(ka, (128.0f - ixb) / ixs); kb = fminf(kb, (-1.0f - ixb) / ixs); }
  else if (ixb <= -1.0f || ixb >= 128.0f) { kb = ka; }
  if (izs > 1e-12f)       { ka = fmaxf(ka, (-1.0f - izb) / izs); kb = fminf(kb, (128.0f - izb) / izs); }
  else if (izs < -1e-12f) { ka = fmaxf(ka, (128.0f - izb) / izs); kb = fminf(kb, (-1.0f - izb) / izs); }
  else if (izb <= -1.0f || izb >= 128.0f) { kb = ka; }
  ka = fmaxf(ka, (float)k0); kb = fminf(kb, (float)(k0 + 16));
  const int kai = (int)ceilf(ka);
  const int kbi = (int)ceilf(kb);
  float sum = 0.0f;
#pragma unroll 2
  for (int k = kai; k < kbi; ++k) {
    const float kf = (float)k;
    const float ix = fmaf(kf, ixs, ixb);
    const float iy = kf * c;
    const float iz = fmaf(kf, izs, izb);
    const float fx = floorf(ix), fy = floorf(iy), fz = floorf(iz);
    const int x0 = (int)fx, y0 = (int)fy, z0 = (int)fz;
    const float wx1 = ix - fx, wy1 = iy - fy, wz1 = iz - fz;
    const float wx0 = 1.0f - wx1, wy0 = 1.0f - wy1, wz0 = 1.0f - wz1;
    const float vx0 = ((unsigned)x0       < 128u) ? wx0 : 0.0f;
    const float vx1 = ((unsigned)(x0 + 1) < 128u) ? wx1 : 0.0f;
    const float vz0 = ((unsigned)z0       < 128u) ? wz0 : 0.0f;
    const float vz1 = ((unsigned)(z0 + 1) < 128u) ? wz1 : 0.0f;
    const int xb2 = min(max(x0, 0), 126);
    const bool inx = (x0 == xb2);
    const float wlo = inx ? vx0 : vx1;
    const float whi = inx ? vx1 : vx0;
    const int zc0 = min(max(z0, 0), 127), zc1 = min(max(z0 + 1, 0), 127);
    const float* base = vol + ((zc0 << 14) + (y0 << 7) + xb2);
    const int dz = (zc1 - zc0) << 14;
    const f2u v00 = *(const f2u*)(base);
    const f2u v01 = *(const f2u*)(base + 128);
    const f2u v10 = *(const f2u*)(base + dz);
    const f2u v11 = *(const f2u*)(base + dz + 128);
    const float s00 = fmaf(whi, v00.y, wlo * v00.x);
    const float s01 = fmaf(whi, v01.y, wlo * v01.x);
    const float s10 = fmaf(whi, v10.y, wlo * v10.x);
    const float s11 = fmaf(whi, v11.y, wlo * v11.x);
    const float s0  = fmaf(wy1, s01, wy0 * s00);
    const float s1  = fmaf(wy1, s11, wy0 * s10);
    sum = fmaf(vz0, s0, sum);
    sum = fmaf(vz1, s1, sum);
  }
  __shared__ float part[256];
  part[tid] = sum;
  __syncthreads();
  if (tid < F_PPB) {
    float tot = 0.0f;
#pragma unroll
    for (int s = 0; s < 8; ++s) tot += part[tid + 32 * s];
    const float ax = Ix * invIy * spacing[0];
    const float az = Iz * invIy * spacing[2];
    const float sy = spacing[1];
    out[gpix] = tot * sqrtf(fmaf(ax, ax, fmaf(az, az, sy * sy)));
  }
}

extern "C" void kernel_launch(void* const* d_in, const int* in_sizes, int n_in,
                              void* d_out, int out_size, void* d_ws, size_t ws_size,
                              hipStream_t stream) {
  const float* vol     = (const float*)d_in[0];   // [1,1,128,128,128] fp32
  const float* poses   = (const float*)d_in[1];   // [4,3] fp32
  const float* spacing = (const float*)d_in[2];   // [3] fp32
  float* out = (float*)d_out;                     // [4,1,180,180] fp32

  const size_t need = (size_t)NG * NPIX * sizeof(float);
  if (ws_size >= need) {
    float* part = (float*)d_ws;
    proj_part_kernel<<<NG * PB_N, 256, 0, stream>>>(vol, poses, part);
    reduce_kernel<<<PB_N, 256, 0, stream>>>(part, poses, spacing, out);
  } else {
    proj_masked_kernel<<<F_NCHUNK, 256, 0, stream>>>(vol, poses, spacing, out);
  }
}

// Round 10
// 28.287 us; speedup vs baseline: 1.6317x; 1.2215x over previous
//
#include <hip/hip_runtime.h>

// Cone-beam projection: D=W=H=128 volume, 180x180 detector, BATCH=4.
// out[b][0][i][j] = dx(b,i,j) * sum_{k=0..127} trilinear(vol, ray(b,i,j,k))
//
// Index-space ray, linear in k:
//   iz(k) = izb + k*izs  (D axis, stride 2^14)
//   iy(k) = k*(127/128)  (W axis, never OOB)
//   ix(k) = ixb + k*ixs  (H axis, stride 1)
// Per-thread loop covers only its valid k-subinterval (ix,iz in (-1,128));
// per-axis masked weights reproduce the reference's zero padding exactly.
//
// SHAPE (round-4 proven best: 27.0us): 256-thr blocks = 32 adjacent-j pixels
// x 8 k-chunks of 16; 4050 blocks (~2x residency, HW refills early-exiting
// dead blocks); coprime swizzle spreads heavy central chunks across CUs.
//
// ROUND-10 LEVER: R4 compiled to VGPR=32 -> only ~1 iteration's 4 gathers in
// flight -> waves ~80% stalled on vmcnt (VALUBusy 27% at occupancy 45%).
// #pragma unroll 4 + __launch_bounds__(256,4) (allows <=128 VGPR; still the
// ~4 waves/SIMD we measured live) lets the compiler keep ~16 independent
// gathers outstanding per wave = 4x memory-level parallelism per wave.
//
// Negative results so far (do not revisit): per-lane 3-phase interior split
// (R5, lane-divergent trip counts); 64px/512-thr blocks (R5/R7); per-call
// pad staging in ws (R8, L2 dirty + flush every replay); XCD k-partition +
// 2-kernel reduce (R9, split tax >= locality gain).

#define RES 180
#define NPIX (4 * RES * RES)       // 129600
#define PPB 32
#define NCHUNK (NPIX / PPB)        // 4050
#define CHUNK_STRIDE 1013          // prime, coprime to 4050

typedef struct __attribute__((packed, aligned(4))) { float x, y; } f2u;

__global__ __launch_bounds__(256, 4) void proj_kernel(
    const float* __restrict__ vol, const float* __restrict__ poses,
    const float* __restrict__ spacing, float* __restrict__ out) {
  const int tid = threadIdx.x;
  const int lp  = tid & 31;       // pixel slot
  const int ks  = tid >> 5;       // k-chunk 0..7 (16 k each)
  const int chunk = (int)(((long long)blockIdx.x * CHUNK_STRIDE) % NCHUNK);
  const int gpix = chunk * PPB + lp;

  const int b   = gpix / (RES * RES);
  const int rem = gpix - b * (RES * RES);
  const int i   = rem / RES;
  const int j   = rem - i * RES;

  const float ex = poses[b * 3 + 0];
  const float ey = poses[b * 3 + 1];
  const float ez = poses[b * 3 + 2];

  const float Ix = ((float)i - 90.0f) - ex;
  const float Iy = -ey;                // ~ +300
  const float Iz = ((float)j - 90.0f) - ez;

  const float c     = 63.5f / 64.0f;   // exact in fp32
  const float invIy = 1.0f / Iy;

  const float izb = fmaf(ex + Ix, c, 63.5f);
  const float izs = Ix * invIy * c;
  const float ixb = fmaf(ez + Iz, c, 63.5f);
  const float ixs = Iz * invIy * c;

  // valid k-interval: ix,iz in (-1,128), k in [k0, k0+16)
  const int k0 = ks * 16;
  float ka = (float)k0, kb = (float)(k0 + 16);
  if (ixs > 1e-12f)       { ka = fmaxf(ka, (-1.0f - ixb) / ixs); kb = fminf(kb, (128.0f - ixb) / ixs); }
  else if (ixs < -1e-12f) { ka = fmaxf(ka, (128.0f - ixb) / ixs); kb = fminf(kb, (-1.0f - ixb) / ixs); }
  else if (ixb <= -1.0f || ixb >= 128.0f) { kb = ka; }
  if (izs > 1e-12f)       { ka = fmaxf(ka, (-1.0f - izb) / izs); kb = fminf(kb, (128.0f - izb) / izs); }
  else if (izs < -1e-12f) { ka = fmaxf(ka, (128.0f - izb) / izs); kb = fminf(kb, (-1.0f - izb) / izs); }
  else if (izb <= -1.0f || izb >= 128.0f) { kb = ka; }
  ka = fmaxf(ka, (float)k0);
  kb = fminf(kb, (float)(k0 + 16));
  const int kai = (int)ceilf(ka);
  const int kbi = (int)ceilf(kb);

  float sum = 0.0f;
#pragma unroll 4
  for (int k = kai; k < kbi; ++k) {
    const float kf = (float)k;
    const float ix = fmaf(kf, ixs, ixb);
    const float iy = kf * c;
    const float iz = fmaf(kf, izs, izb);

    const float fx = floorf(ix), fy = floorf(iy), fz = floorf(iz);
    const int x0 = (int)fx, y0 = (int)fy, z0 = (int)fz;

    const float wx1 = ix - fx, wy1 = iy - fy, wz1 = iz - fz;
    const float wx0 = 1.0f - wx1, wy0 = 1.0f - wy1, wz0 = 1.0f - wz1;

    // x/z per-axis masked weights == reference's zero padding
    const float vx0 = ((unsigned)x0       < 128u) ? wx0 : 0.0f;
    const float vx1 = ((unsigned)(x0 + 1) < 128u) ? wx1 : 0.0f;
    const float vz0 = ((unsigned)z0       < 128u) ? wz0 : 0.0f;
    const float vz1 = ((unsigned)(z0 + 1) < 128u) ? wz1 : 0.0f;

    // one f2u covers both x-neighbors; at edges swap weights instead
    const int xb2 = min(max(x0, 0), 126);
    const bool inx = (x0 == xb2);
    const float wlo = inx ? vx0 : vx1;
    const float whi = inx ? vx1 : vx0;

    const int zc0 = min(max(z0, 0), 127), zc1 = min(max(z0 + 1, 0), 127);
    const float* base = vol + ((zc0 << 14) + (y0 << 7) + xb2);
    const int dz = (zc1 - zc0) << 14;

    const f2u v00 = *(const f2u*)(base);
    const f2u v01 = *(const f2u*)(base + 128);
    const f2u v10 = *(const f2u*)(base + dz);
    const f2u v11 = *(const f2u*)(base + dz + 128);

    const float s00 = fmaf(whi, v00.y, wlo * v00.x);
    const float s01 = fmaf(whi, v01.y, wlo * v01.x);
    const float s10 = fmaf(whi, v10.y, wlo * v10.x);
    const float s11 = fmaf(whi, v11.y, wlo * v11.x);
    const float s0  = fmaf(wy1, s01, wy0 * s00);
    const float s1  = fmaf(wy1, s11, wy0 * s10);

    sum = fmaf(vz0, s0, sum);
    sum = fmaf(vz1, s1, sum);
  }

  __shared__ float part[256];
  part[tid] = sum;
  __syncthreads();

  if (tid < PPB) {
    float tot = 0.0f;
#pragma unroll
    for (int s = 0; s < 8; ++s) tot += part[tid + 32 * s];
    const float ax = Ix * invIy * spacing[0];
    const float az = Iz * invIy * spacing[2];
    const float sy = spacing[1];
    out[gpix] = tot * sqrtf(fmaf(ax, ax, fmaf(az, az, sy * sy)));
  }
}

extern "C" void kernel_launch(void* const* d_in, const int* in_sizes, int n_in,
                              void* d_out, int out_size, void* d_ws, size_t ws_size,
                              hipStream_t stream) {
  const float* vol     = (const float*)d_in[0];   // [1,1,128,128,128] fp32
  const float* poses   = (const float*)d_in[1];   // [4,3] fp32
  const float* spacing = (const float*)d_in[2];   // [3] fp32
  float* out = (float*)d_out;                     // [4,1,180,180] fp32

  proj_kernel<<<NCHUNK, 256, 0, stream>>>(vol, poses, spacing, out);
}

// Round 11
// 25.916 us; speedup vs baseline: 1.7810x; 1.0915x over previous
//
#include <hip/hip_runtime.h>

// Cone-beam projection: D=W=H=128 volume, 180x180 detector, BATCH=4.
// out[b][0][i][j] = dx(b,i,j) * sum_{k=0..127} trilinear(vol, ray(b,i,j,k))
//
// Index-space ray, linear in k:
//   iz(k) = izb + k*izs  (D axis, stride 2^14)
//   iy(k) = k*(127/128)  (W axis, never OOB)
//   ix(k) = ixb + k*ixs  (H axis, stride 1)
// Per-thread work covers only valid k (ix,iz in (-1,128)); per-axis masked
// weights reproduce the reference's zero padding exactly.
//
// SHAPE: R4-proven (27.0us): 256-thr blocks = 32 adjacent-j pixels x 8
// k-threads; 4050 blocks (~2x residency); coprime swizzle for CU balance.
//
// ROUND-11 LEVER (per-wave MLP): each k-thread owns TWO mirrored 8-k chunks
// (c and 15-c; near/far mirror -> correlated lengths -> balanced). Two
// independent bodies per loop iteration = 8 gathers in flight before any
// wait, with NO unroll (R10 showed unroll-4 never executes: trips < 8).
//
// Negative results (do not revisit): per-lane 3-phase interior split (R5);
// 64px/512-thr blocks (R5/R7); per-call pad staging (R8: L2 dirty/flush per
// replay); XCD k-partition + reduce kernel (R9: split tax >= locality win);
// #pragma unroll 4 on short trips (R10: remainder-dominated).

#define RES 180
#define NPIX (4 * RES * RES)       // 129600
#define PPB 32
#define NCHUNK (NPIX / PPB)        // 4050
#define CHUNK_STRIDE 1013          // prime, coprime to 4050

typedef struct __attribute__((packed, aligned(4))) { float x, y; } f2u;

__global__ __launch_bounds__(256) void proj_kernel(
    const float* __restrict__ vol, const float* __restrict__ poses,
    const float* __restrict__ spacing, float* __restrict__ out) {
  const int tid = threadIdx.x;
  const int lp  = tid & 31;       // pixel slot
  const int ks  = tid >> 5;       // k-thread 0..7
  const int chunk = (int)(((long long)blockIdx.x * CHUNK_STRIDE) % NCHUNK);
  const int gpix = chunk * PPB + lp;

  const int b   = gpix / (RES * RES);
  const int rem = gpix - b * (RES * RES);
  const int i   = rem / RES;
  const int j   = rem - i * RES;

  const float ex = poses[b * 3 + 0];
  const float ey = poses[b * 3 + 1];
  const float ez = poses[b * 3 + 2];

  const float Ix = ((float)i - 90.0f) - ex;
  const float Iy = -ey;                // ~ +300
  const float Iz = ((float)j - 90.0f) - ez;

  const float c     = 63.5f / 64.0f;   // exact in fp32
  const float invIy = 1.0f / Iy;

  const float izb = fmaf(ex + Ix, c, 63.5f);
  const float izs = Ix * invIy * c;
  const float ixb = fmaf(ez + Iz, c, 63.5f);
  const float ixs = Iz * invIy * c;

  // ---- global valid k-interval (once): ix,iz in (-1,128), k in [0,128) ----
  float ka = 0.0f, kb = 128.0f;
  if (ixs > 1e-12f)       { ka = fmaxf(ka, (-1.0f - ixb) / ixs); kb = fminf(kb, (128.0f - ixb) / ixs); }
  else if (ixs < -1e-12f) { ka = fmaxf(ka, (128.0f - ixb) / ixs); kb = fminf(kb, (-1.0f - ixb) / ixs); }
  else if (ixb <= -1.0f || ixb >= 128.0f) { kb = ka; }
  if (izs > 1e-12f)       { ka = fmaxf(ka, (-1.0f - izb) / izs); kb = fminf(kb, (128.0f - izb) / izs); }
  else if (izs < -1e-12f) { ka = fmaxf(ka, (128.0f - izb) / izs); kb = fminf(kb, (-1.0f - izb) / izs); }
  else if (izb <= -1.0f || izb >= 128.0f) { kb = ka; }
  ka = fmaxf(ka, 0.0f);
  kb = fminf(kb, 128.0f);
  const int kai = (int)ceilf(ka);
  const int kbi = (int)ceilf(kb);   // masks keep edges exact

  // ---- two mirrored 8-k chunks per thread ----
  const int c1 = ks;              // k in [8c1, 8c1+8)
  const int c2 = 15 - ks;         // k in [8c2, 8c2+8)
  const int a1 = max(kai, 8 * c1), b1 = min(kbi, 8 * c1 + 8);
  const int a2 = max(kai, 8 * c2), b2 = min(kbi, 8 * c2 + 8);
  const int n1 = max(0, b1 - a1);
  const int n2 = max(0, b2 - a2);
  const int nt = max(n1, n2);

  float sum = 0.0f;

#define BODY(kk)                                                               \
  {                                                                            \
    const int k = (kk);                                                        \
    const float kf = (float)k;                                                 \
    const float ix = fmaf(kf, ixs, ixb);                                       \
    const float iy = kf * c;                                                   \
    const float iz = fmaf(kf, izs, izb);                                       \
    const float fx = floorf(ix), fy = floorf(iy), fz = floorf(iz);             \
    const int x0 = (int)fx, y0 = (int)fy, z0 = (int)fz;                        \
    const float wx1 = ix - fx, wy1 = iy - fy, wz1 = iz - fz;                   \
    const float wx0 = 1.0f - wx1, wy0 = 1.0f - wy1, wz0 = 1.0f - wz1;          \
    const float vx0 = ((unsigned)x0       < 128u) ? wx0 : 0.0f;                \
    const float vx1 = ((unsigned)(x0 + 1) < 128u) ? wx1 : 0.0f;                \
    const float vz0 = ((unsigned)z0       < 128u) ? wz0 : 0.0f;                \
    const float vz1 = ((unsigned)(z0 + 1) < 128u) ? wz1 : 0.0f;                \
    const int xb2 = min(max(x0, 0), 126);                                      \
    const bool inx = (x0 == xb2);                                              \
    const float wlo = inx ? vx0 : vx1;                                         \
    const float whi = inx ? vx1 : vx0;                                         \
    const int zc0 = min(max(z0, 0), 127), zc1 = min(max(z0 + 1, 0), 127);      \
    const float* base = vol + ((zc0 << 14) + (y0 << 7) + xb2);                 \
    const int dz = (zc1 - zc0) << 14;                                          \
    const f2u v00 = *(const f2u*)(base);                                       \
    const f2u v01 = *(const f2u*)(base + 128);                                 \
    const f2u v10 = *(const f2u*)(base + dz);                                  \
    const f2u v11 = *(const f2u*)(base + dz + 128);                            \
    const float s00 = fmaf(whi, v00.y, wlo * v00.x);                           \
    const float s01 = fmaf(whi, v01.y, wlo * v01.x);                           \
    const float s10 = fmaf(whi, v10.y, wlo * v10.x);                           \
    const float s11 = fmaf(whi, v11.y, wlo * v11.x);                           \
    const float s0  = fmaf(wy1, s01, wy0 * s00);                               \
    const float s1  = fmaf(wy1, s11, wy0 * s10);                               \
    sum = fmaf(vz0, s0, sum);                                                  \
    sum = fmaf(vz1, s1, sum);                                                  \
  }

  for (int t = 0; t < nt; ++t) {
    if (t < n1) BODY(a1 + t)
    if (t < n2) BODY(a2 + t)
  }
#undef BODY

  __shared__ float part[256];
  part[tid] = sum;
  __syncthreads();

  if (tid < PPB) {
    float tot = 0.0f;
#pragma unroll
    for (int s = 0; s < 8; ++s) tot += part[tid + 32 * s];
    const float ax = Ix * invIy * spacing[0];
    const float az = Iz * invIy * spacing[2];
    const float sy = spacing[1];
    out[gpix] = tot * sqrtf(fmaf(ax, ax, fmaf(az, az, sy * sy)));
  }
}

extern "C" void kernel_launch(void* const* d_in, const int* in_sizes, int n_in,
                              void* d_out, int out_size, void* d_ws, size_t ws_size,
                              hipStream_t stream) {
  const float* vol     = (const float*)d_in[0];   // [1,1,128,128,128] fp32
  const float* poses   = (const float*)d_in[1];   // [4,3] fp32
  const float* spacing = (const float*)d_in[2];   // [3] fp32
  float* out = (float*)d_out;                     // [4,1,180,180] fp32

  proj_kernel<<<NCHUNK, 256, 0, stream>>>(vol, poses, spacing, out);
}